// Round 10
// baseline (1827.019 us; speedup 1.0000x reference)
//
#include <hip/hip_runtime.h>
#include <math.h>

#define XDIM 521
#define TDIM 49
#define TPAD 52
#define XT (XDIM*TPAD)   /* 27092 */
#define NBTOT 32
#define NC 64
#define NS 512
#define NTO 40
#define NTIN 10
#define CIN 14
#define PI_D 3.14159265358979323846

// exact-path gelu (used only in init-free contexts if needed)
__device__ __forceinline__ float gelu_f(float x){
  return 0.5f*x*(1.0f + erff(x*0.70710678118654752440f));
}

// fast gelu: A&S 7.1.26 erf approximation, |err_erf| <= 1.5e-7
// gelu(x) = 0.5 x (1 + erf(x/sqrt(2)))
__device__ __forceinline__ float gelu_fast(float x){
  float z = x*0.70710678118654752440f;
  float az = fabsf(z);
  float t = __frcp_rn(fmaf(0.3275911f, az, 1.0f));
  float p = fmaf(1.061405429f, t, -1.453152027f);
  p = fmaf(p, t, 1.421413741f);
  p = fmaf(p, t, -0.284496736f);
  p = fmaf(p, t, 0.254829592f);
  p = p*t;
  float e = __expf(-az*az);
  float erfa = fmaf(-p, e, 1.0f);          // erf(|z|)
  float erfz = (z < 0.f) ? -erfa : erfa;
  return 0.5f*x*(1.0f + erfz);
}

// ---------------- init: twiddle tables + small transposed weight copies ----------------
__global__ void k_init(float* __restrict__ TXC, float* __restrict__ TXS,
                       float* __restrict__ TTC, float* __restrict__ TTS,
                       float* __restrict__ ITC, float* __restrict__ ITS,
                       float* __restrict__ WT0, float* __restrict__ WT1, float* __restrict__ WTC,
                       const float* __restrict__ fc0_w, const float* __restrict__ fc1_w,
                       const float* __restrict__ w_conv){
  int i = blockIdx.x*256 + threadIdx.x;
  if (i < XDIM*16){
    int x = i >> 4, kx = i & 15;
    double ang = 2.0*PI_D*(double)((x*kx)%XDIM)/(double)XDIM;
    TXC[i] = (float)cos(ang);
    TXS[i] = (float)sin(ang);
  }
  if (i < TDIM*16){
    int t = i >> 4, kt = i & 15;
    double ang = 2.0*PI_D*(double)((t*kt)%TDIM)/(double)TDIM;
    TTC[i] = (float)cos(ang);
    TTS[i] = (float)sin(ang);
    double nrm = ((kt==0)?1.0:2.0)/(double)(XDIM*TDIM);
    ITC[i] = (float)(nrm*cos(ang));
    ITS[i] = (float)(nrm*sin(ang));
  }
  if (i < 64*16){               // fc0_w (14,64) -> WT0[c][16]
    int c = i >> 4, k = i & 15;
    WT0[i] = (k < CIN) ? fc0_w[k*64 + c] : 0.f;
  }
  if (i < 128*64){              // fc1_w (64,128) -> WT1[j][c]
    int j = i >> 6, c = i & 63;
    WT1[i] = fc1_w[c*128 + j];
  }
  if (i < 4*64*64){             // w_conv (4,o,c) -> WTC[l][c][o]
    int l = i >> 12, r = i & 4095, c = r >> 6, o = r & 63;
    WTC[i] = w_conv[(l*64 + o)*64 + c];
  }
}

// ---------------- fc0 + grid-feature build + transpose + pad (position-parallel) ----------------
__global__ void k_fc0(const float* __restrict__ u, const float* __restrict__ xg,
                      const float* __restrict__ tg, const float* __restrict__ par,
                      const float* __restrict__ WT0, const float* __restrict__ fc0_b,
                      float* __restrict__ v, int b0){
  int bl = blockIdx.y;
  int b  = b0 + bl;
  int p = blockIdx.x*256 + threadIdx.x;
  if (p >= XT) return;
  int x = p / TPAD, t = p - x*TPAD;
  bool valid = (x < NS) && (t < NTO);
  float in[CIN];
  if (valid){
    #pragma unroll
    for (int k=0;k<NTIN;k++) in[k] = u[((size_t)(b*NS+x))*NTIN + k];
    in[10] = par[b*2+0]; in[11] = par[b*2+1];
    in[12] = xg[b*NS + x];
    in[13] = tg[b*NTO + t];
  } else {
    #pragma unroll
    for (int k=0;k<CIN;k++) in[k] = 0.f;
  }
  size_t base = ((size_t)bl*NC)*XT + p;
  for (int c=0;c<NC;c++){
    float acc = valid ? fc0_b[c] : 0.f;
    #pragma unroll
    for (int k=0;k<CIN;k++) acc = fmaf(in[k], WT0[c*16+k], acc);
    v[base + (size_t)c*XT] = acc;
  }
}

// ---- reduce tail: combine this block's 4-wave DFT-x partials, T-DFT, write partial cV ----
__device__ __forceinline__ void dft_reduce_emit(
    float (&ar)[16], float (&ai)[16], int w, int t,
    const float* __restrict__ TTC, const float* __restrict__ TTS,
    float* __restrict__ cVR, float* __restrict__ cVI, int bo, int NCB){
  __shared__ float redR[4*16*50], redI[4*16*50];
  if (t < TDIM){
    #pragma unroll
    for (int kx=0;kx<16;kx++){
      redR[(w*16+kx)*50 + t] = ar[kx];
      redI[(w*16+kx)*50 + t] = ai[kx];
    }
  }
  __syncthreads();
  int tid = w*64 + t;
  for (int q = tid; q < 784; q += 256){
    int kx = q/49, tt = q - kx*49;
    int idx = kx*50 + tt;
    float sR = redR[idx] + redR[800+idx] + redR[1600+idx] + redR[2400+idx];
    float sI = redI[idx] + redI[800+idx] + redI[1600+idx] + redI[2400+idx];
    redR[idx] = sR; redI[idx] = sI;
  }
  __syncthreads();
  int kx = tid >> 4, kt = tid & 15;
  float accR=0.f, accI=0.f;
  for (int tt=0; tt<TDIM; tt++){
    float vr = redR[kx*50+tt], vi = redI[kx*50+tt];
    float c = TTC[tt*16+kt], s = TTS[tt*16+kt];
    accR += vr*c + vi*s;
    accI += vi*c - vr*s;
  }
  cVR[(size_t)tid*NCB + bo] = accR;
  cVI[(size_t)tid*NCB + bo] = accI;
}

// ---------------- standalone DFT-x + DFT-t of a plane (layer 0), mirror-paired, 2-way split ----
__global__ void __launch_bounds__(256) k_dftxt(const float* __restrict__ v,
    const float* __restrict__ TXC, const float* __restrict__ TXS,
    const float* __restrict__ TTC, const float* __restrict__ TTS,
    float* __restrict__ cVR0, float* __restrict__ cVI0,
    float* __restrict__ cVR1, float* __restrict__ cVI1, int NCB){
  int bo = blockIdx.x >> 1, h = blockIdx.x & 1;
  int w = threadIdx.x >> 6, t = threadIdx.x & 63;
  bool act = (t < TDIM);
  const float* vp = v + (size_t)bo*XT + (act ? t : 0);
  float ar[16], ai[16];
  #pragma unroll
  for (int k=0;k<16;k++){ ar[k]=0.f; ai[k]=0.f; }
  if (h == 0 && w == 0){
    float v0 = act ? vp[0] : 0.f;      // x=0: c=1, s=0 for all kx
    #pragma unroll
    for (int k=0;k<16;k++) ar[k] += v0;
  }
  int chunk = h*4 + w;                  // 0..7 over 260 mirror pairs
  int p0 = 1 + (chunk*65)/2, p1 = 1 + ((chunk+1)*65)/2;
  for (int p=p0; p<p1; p++){
    int xa = p, xb = XDIM - p;
    float va = act ? vp[xa*TPAD] : 0.f;
    float vbv= act ? vp[xb*TPAD] : 0.f;
    float sp = va + vbv, sm = va - vbv;
    const float4 tc0 = *reinterpret_cast<const float4*>(TXC + xa*16 + 0);
    const float4 tc1 = *reinterpret_cast<const float4*>(TXC + xa*16 + 4);
    const float4 tc2 = *reinterpret_cast<const float4*>(TXC + xa*16 + 8);
    const float4 tc3 = *reinterpret_cast<const float4*>(TXC + xa*16 + 12);
    const float4 ts0 = *reinterpret_cast<const float4*>(TXS + xa*16 + 0);
    const float4 ts1 = *reinterpret_cast<const float4*>(TXS + xa*16 + 4);
    const float4 ts2 = *reinterpret_cast<const float4*>(TXS + xa*16 + 8);
    const float4 ts3 = *reinterpret_cast<const float4*>(TXS + xa*16 + 12);
    ar[0]  = fmaf(sp, tc0.x, ar[0]);  ai[0]  = fmaf(-sm, ts0.x, ai[0]);
    ar[1]  = fmaf(sp, tc0.y, ar[1]);  ai[1]  = fmaf(-sm, ts0.y, ai[1]);
    ar[2]  = fmaf(sp, tc0.z, ar[2]);  ai[2]  = fmaf(-sm, ts0.z, ai[2]);
    ar[3]  = fmaf(sp, tc0.w, ar[3]);  ai[3]  = fmaf(-sm, ts0.w, ai[3]);
    ar[4]  = fmaf(sp, tc1.x, ar[4]);  ai[4]  = fmaf(-sm, ts1.x, ai[4]);
    ar[5]  = fmaf(sp, tc1.y, ar[5]);  ai[5]  = fmaf(-sm, ts1.y, ai[5]);
    ar[6]  = fmaf(sp, tc1.z, ar[6]);  ai[6]  = fmaf(-sm, ts1.z, ai[6]);
    ar[7]  = fmaf(sp, tc1.w, ar[7]);  ai[7]  = fmaf(-sm, ts1.w, ai[7]);
    ar[8]  = fmaf(sp, tc2.x, ar[8]);  ai[8]  = fmaf(-sm, ts2.x, ai[8]);
    ar[9]  = fmaf(sp, tc2.y, ar[9]);  ai[9]  = fmaf(-sm, ts2.y, ai[9]);
    ar[10] = fmaf(sp, tc2.z, ar[10]); ai[10] = fmaf(-sm, ts2.z, ai[10]);
    ar[11] = fmaf(sp, tc2.w, ar[11]); ai[11] = fmaf(-sm, ts2.w, ai[11]);
    ar[12] = fmaf(sp, tc3.x, ar[12]); ai[12] = fmaf(-sm, ts3.x, ai[12]);
    ar[13] = fmaf(sp, tc3.y, ar[13]); ai[13] = fmaf(-sm, ts3.y, ai[13]);
    ar[14] = fmaf(sp, tc3.z, ar[14]); ai[14] = fmaf(-sm, ts3.z, ai[14]);
    ar[15] = fmaf(sp, tc3.w, ar[15]); ai[15] = fmaf(-sm, ts3.w, ai[15]);
  }
  dft_reduce_emit(ar, ai, w, t, TTC, TTS, h ? cVR1 : cVR0, h ? cVI1 : cVI0, bo, NCB);
}

// ---------------- per-mode 64x64 complex channel mix (cV = half0 + half1) ----------------
__global__ void k_spec(const float* __restrict__ swr, const float* __restrict__ swi,
                       const float* __restrict__ cVR0, const float* __restrict__ cVI0,
                       const float* __restrict__ cVR1, const float* __restrict__ cVI1,
                       float* __restrict__ cOR, float* __restrict__ cOI, int l, int NCB){
  int m = blockIdx.x;           // 0..255 = kx*16+kt
  __shared__ float wr[4096], wi[4096];
  __shared__ float vr[32*65], vi[32*65];
  const size_t wb = (size_t)l*64*64*256 + m;
  for (int q = threadIdx.x; q < 4096; q += 256){
    wr[q] = swr[wb + (size_t)q*256];
    wi[q] = swi[wb + (size_t)q*256];
  }
  for (int q = threadIdx.x; q < NCB; q += 256){
    int b=q>>6, i=q&63;
    vr[b*65+i] = cVR0[(size_t)m*NCB+q] + cVR1[(size_t)m*NCB+q];
    vi[b*65+i] = cVI0[(size_t)m*NCB+q] + cVI1[(size_t)m*NCB+q];
  }
  __syncthreads();
  int b = threadIdx.x >> 3, og = threadIdx.x & 7;
  if (b*64 < NCB){
    float oR[8], oI[8];
    #pragma unroll
    for (int j=0;j<8;j++){ oR[j]=0.f; oI[j]=0.f; }
    for (int i=0;i<64;i++){
      float arv = vr[b*65+i], aiv = vi[b*65+i];
      #pragma unroll
      for (int j=0;j<8;j++){
        float wrv = wr[i*64 + og*8 + j], wiv = wi[i*64 + og*8 + j];
        oR[j] = fmaf(arv,wrv,fmaf(-aiv,wiv,oR[j]));
        oI[j] = fmaf(arv,wiv,fmaf( aiv,wrv,oI[j]));
      }
    }
    #pragma unroll
    for (int j=0;j<8;j++){
      cOR[(size_t)m*NCB + b*64 + og*8 + j] = oR[j];
      cOI[(size_t)m*NCB + b*64 + og*8 + j] = oI[j];
    }
  }
}

// ---------------- inverse part 1: kt -> t expansion (tiny), G into VX buffers ----------------
__global__ void __launch_bounds__(256) k_invG(const float* __restrict__ cOR, const float* __restrict__ cOI,
    const float* __restrict__ ITC, const float* __restrict__ ITS,
    float* __restrict__ GR, float* __restrict__ GI, int NCB){
  int bo = blockIdx.x;
  __shared__ float lcr[256], lci[256];
  int q = threadIdx.x;
  lcr[q] = cOR[(size_t)q*NCB + bo];
  lci[q] = cOI[(size_t)q*NCB + bo];
  __syncthreads();
  int kx = q >> 4, tq = q & 15;
  for (int t = tq; t < TDIM; t += 16){
    float gr=0.f, gi=0.f;
    #pragma unroll
    for (int kt=0;kt<16;kt++){
      float cr = lcr[kx*16+kt], ci = lci[kx*16+kt];
      float wc = ITC[t*16+kt], ws = ITS[t*16+kt];
      gr = fmaf(cr,wc,fmaf(-ci,ws,gr));
      gi = fmaf(cr,ws,fmaf( ci,wc,gi));
    }
    GR[(size_t)bo*784 + kx*TDIM + t] = gr;
    GI[(size_t)bo*784 + kx*TDIM + t] = gi;
  }
}

// ---------------- pointwise conv, IN-PLACE: v <- W*v + bias (u2 stored) ----------------
__global__ void __launch_bounds__(256) k_conv(float* __restrict__ v,
    const float* __restrict__ WTC, const float* __restrict__ w_bias, int l){
  int bl = blockIdx.y;
  int p = blockIdx.x*512 + threadIdx.x*2;
  if (p >= XT) return;
  const float* wl = WTC + l*4096;    // [c][o]
  float a0[64], a1[64];
  #pragma unroll
  for (int o=0;o<64;o++){ a0[o]=0.f; a1[o]=0.f; }
  const size_t bb = (size_t)bl*NC*XT;
  for (int c=0;c<NC;c++){
    const float2 vv = *reinterpret_cast<const float2*>(v + bb + (size_t)c*XT + p);
    #pragma unroll
    for (int o=0;o<64;o++){
      float wv = wl[c*64+o];          // uniform -> s_load
      a0[o] = fmaf(vv.x, wv, a0[o]);
      a1[o] = fmaf(vv.y, wv, a1[o]);
    }
  }
  #pragma unroll
  for (int o=0;o<64;o++){
    float bias = w_bias[l*64+o];
    float2 rr; rr.x = a0[o]+bias; rr.y = a1[o]+bias;
    *reinterpret_cast<float2*>(v + bb + (size_t)o*XT + p) = rr;
  }
}

// ---- fused inverse-x (mirror-paired) + add + gelu + in-register DFT emit, 2-way split ----
// block pair (bo,h); v holds u2 (conv output); v <- [gelu](u1 + u2); if EMIT, emits partial cV
template<int GELU, int EMIT>
__global__ void __launch_bounds__(256) k_inv2dft(const float* __restrict__ GR, const float* __restrict__ GI,
    const float* __restrict__ TXC, const float* __restrict__ TXS,
    const float* __restrict__ TTC, const float* __restrict__ TTS,
    float* __restrict__ v,
    float* __restrict__ cVR0, float* __restrict__ cVI0,
    float* __restrict__ cVR1, float* __restrict__ cVI1, int NCB){
  int bo = blockIdx.x >> 1, h = blockIdx.x & 1;
  int w = threadIdx.x >> 6, t = threadIdx.x & 63;
  bool act = (t < TDIM);
  int tcl = act ? t : 0;
  float gr[16], gi[16];
  #pragma unroll
  for (int kx=0;kx<16;kx++){
    gr[kx] = GR[(size_t)bo*784 + kx*TDIM + tcl];
    gi[kx] = GI[(size_t)bo*784 + kx*TDIM + tcl];
  }
  float ar[16], ai[16];
  #pragma unroll
  for (int k=0;k<16;k++){ ar[k]=0.f; ai[k]=0.f; }
  float* vb = v + (size_t)bo*XT;
  if (h == 0 && w == 0){                        // x = 0: c=1, s=0
    float s1 = 0.f;
    #pragma unroll
    for (int k=0;k<16;k++) s1 += gr[k];
    float r = 0.f;
    if (act){
      r = s1 + vb[t];
      if (GELU) r = gelu_fast(r);
    }
    if (t < TPAD) vb[t] = r;
    if (EMIT){
      #pragma unroll
      for (int k=0;k<16;k++) ar[k] += r;
    }
  }
  int chunk = h*4 + w;                  // 0..7 over 260 mirror pairs
  int p0 = 1 + (chunk*65)/2, p1 = 1 + ((chunk+1)*65)/2;
  for (int p=p0; p<p1; p++){
    int xa = p, xb = XDIM - p;
    const float4 tc0 = *reinterpret_cast<const float4*>(TXC + xa*16 + 0);
    const float4 tc1 = *reinterpret_cast<const float4*>(TXC + xa*16 + 4);
    const float4 tc2 = *reinterpret_cast<const float4*>(TXC + xa*16 + 8);
    const float4 tc3 = *reinterpret_cast<const float4*>(TXC + xa*16 + 12);
    const float4 ts0 = *reinterpret_cast<const float4*>(TXS + xa*16 + 0);
    const float4 ts1 = *reinterpret_cast<const float4*>(TXS + xa*16 + 4);
    const float4 ts2 = *reinterpret_cast<const float4*>(TXS + xa*16 + 8);
    const float4 ts3 = *reinterpret_cast<const float4*>(TXS + xa*16 + 12);
    float s1, s2;
    s1  = gr[0]*tc0.x;             s2  = gi[0]*ts0.x;
    s1  = fmaf(gr[1],  tc0.y, s1); s2  = fmaf(gi[1],  ts0.y, s2);
    s1  = fmaf(gr[2],  tc0.z, s1); s2  = fmaf(gi[2],  ts0.z, s2);
    s1  = fmaf(gr[3],  tc0.w, s1); s2  = fmaf(gi[3],  ts0.w, s2);
    s1  = fmaf(gr[4],  tc1.x, s1); s2  = fmaf(gi[4],  ts1.x, s2);
    s1  = fmaf(gr[5],  tc1.y, s1); s2  = fmaf(gi[5],  ts1.y, s2);
    s1  = fmaf(gr[6],  tc1.z, s1); s2  = fmaf(gi[6],  ts1.z, s2);
    s1  = fmaf(gr[7],  tc1.w, s1); s2  = fmaf(gi[7],  ts1.w, s2);
    s1  = fmaf(gr[8],  tc2.x, s1); s2  = fmaf(gi[8],  ts2.x, s2);
    s1  = fmaf(gr[9],  tc2.y, s1); s2  = fmaf(gi[9],  ts2.y, s2);
    s1  = fmaf(gr[10], tc2.z, s1); s2  = fmaf(gi[10], ts2.z, s2);
    s1  = fmaf(gr[11], tc2.w, s1); s2  = fmaf(gi[11], ts2.w, s2);
    s1  = fmaf(gr[12], tc3.x, s1); s2  = fmaf(gi[12], ts3.x, s2);
    s1  = fmaf(gr[13], tc3.y, s1); s2  = fmaf(gi[13], ts3.y, s2);
    s1  = fmaf(gr[14], tc3.z, s1); s2  = fmaf(gi[14], ts3.z, s2);
    s1  = fmaf(gr[15], tc3.w, s1); s2  = fmaf(gi[15], ts3.w, s2);
    float accA = s1 - s2, accB = s1 + s2;
    float rA = 0.f, rB = 0.f;
    if (act){
      rA = accA + vb[(size_t)xa*TPAD + t];
      rB = accB + vb[(size_t)xb*TPAD + t];
      if (GELU){ rA = gelu_fast(rA); rB = gelu_fast(rB); }
    }
    if (t < TPAD){
      vb[(size_t)xa*TPAD + t] = rA;
      vb[(size_t)xb*TPAD + t] = rB;
    }
    if (EMIT){
      float sp = rA + rB, sm = rA - rB;
      ar[0]  = fmaf(sp, tc0.x, ar[0]);  ai[0]  = fmaf(-sm, ts0.x, ai[0]);
      ar[1]  = fmaf(sp, tc0.y, ar[1]);  ai[1]  = fmaf(-sm, ts0.y, ai[1]);
      ar[2]  = fmaf(sp, tc0.z, ar[2]);  ai[2]  = fmaf(-sm, ts0.z, ai[2]);
      ar[3]  = fmaf(sp, tc0.w, ar[3]);  ai[3]  = fmaf(-sm, ts0.w, ai[3]);
      ar[4]  = fmaf(sp, tc1.x, ar[4]);  ai[4]  = fmaf(-sm, ts1.x, ai[4]);
      ar[5]  = fmaf(sp, tc1.y, ar[5]);  ai[5]  = fmaf(-sm, ts1.y, ai[5]);
      ar[6]  = fmaf(sp, tc1.z, ar[6]);  ai[6]  = fmaf(-sm, ts1.z, ai[6]);
      ar[7]  = fmaf(sp, tc1.w, ar[7]);  ai[7]  = fmaf(-sm, ts1.w, ai[7]);
      ar[8]  = fmaf(sp, tc2.x, ar[8]);  ai[8]  = fmaf(-sm, ts2.x, ai[8]);
      ar[9]  = fmaf(sp, tc2.y, ar[9]);  ai[9]  = fmaf(-sm, ts2.y, ai[9]);
      ar[10] = fmaf(sp, tc2.z, ar[10]); ai[10] = fmaf(-sm, ts2.z, ai[10]);
      ar[11] = fmaf(sp, tc2.w, ar[11]); ai[11] = fmaf(-sm, ts2.w, ai[11]);
      ar[12] = fmaf(sp, tc3.x, ar[12]); ai[12] = fmaf(-sm, ts3.x, ai[12]);
      ar[13] = fmaf(sp, tc3.y, ar[13]); ai[13] = fmaf(-sm, ts3.y, ai[13]);
      ar[14] = fmaf(sp, tc3.z, ar[14]); ai[14] = fmaf(-sm, ts3.z, ai[14]);
      ar[15] = fmaf(sp, tc3.w, ar[15]); ai[15] = fmaf(-sm, ts3.w, ai[15]);
    }
  }
  if (EMIT) dft_reduce_emit(ar, ai, w, t, TTC, TTS, h ? cVR1 : cVR0, h ? cVI1 : cVI0, bo, NCB);
}

// ---------------- crop + fc1 + gelu + fc2 (split accumulators, fast gelu) ----------------
__global__ void k_final(const float* __restrict__ v, const float* __restrict__ WT1,
                        const float* __restrict__ fc1_b, const float* __restrict__ fc2_w,
                        const float* __restrict__ fc2_b, float* __restrict__ out, int b0){
  int bl = blockIdx.y;
  int pp = blockIdx.x*256 + threadIdx.x;    // 512*40 = 20480 exactly
  int s = pp / NTO, to = pp - s*NTO;
  float vr[64];
  size_t vb = (size_t)bl*NC*XT + (size_t)s*TPAD + to;
  #pragma unroll
  for (int c=0;c<64;c++) vr[c] = v[vb + (size_t)c*XT];
  float accA = fc2_b[0], accB = 0.f;
  for (int j=0;j<128;j++){
    const float* wj = WT1 + j*64;
    float h0 = fc1_b[j], h1 = 0.f, h2 = 0.f, h3 = 0.f;
    #pragma unroll
    for (int c=0;c<64;c+=4){
      h0 = fmaf(vr[c+0], wj[c+0], h0);
      h1 = fmaf(vr[c+1], wj[c+1], h1);
      h2 = fmaf(vr[c+2], wj[c+2], h2);
      h3 = fmaf(vr[c+3], wj[c+3], h3);
    }
    float h = (h0+h1)+(h2+h3);
    h = gelu_fast(h);
    if (j & 1) accB = fmaf(h, fc2_w[j], accB);
    else       accA = fmaf(h, fc2_w[j], accA);
  }
  out[((size_t)(b0+bl))*20480 + pp] = accA + accB;
}

extern "C" void kernel_launch(void* const* d_in, const int* in_sizes, int n_in,
                              void* d_out, int out_size, void* d_ws, size_t ws_size,
                              hipStream_t stream){
  const float* u     = (const float*)d_in[0];
  const float* xg    = (const float*)d_in[1];
  const float* tg    = (const float*)d_in[2];
  const float* par   = (const float*)d_in[3];
  const float* fc0_w = (const float*)d_in[4];
  const float* fc0_b = (const float*)d_in[5];
  const float* swr   = (const float*)d_in[6];
  const float* swi   = (const float*)d_in[7];
  const float* wconv = (const float*)d_in[8];
  const float* wbias = (const float*)d_in[9];
  const float* fc1_w = (const float*)d_in[10];
  const float* fc1_b = (const float*)d_in[11];
  const float* fc2_w = (const float*)d_in[12];
  const float* fc2_b = (const float*)d_in[13];

  // pick largest batch chunk whose workspace fits ws_size (same formula as rounds 5-9)
  int nb = NBTOT;
  while (nb > 1){
    size_t need = (45408ull + (size_t)nb*64ull*29684ull) * 4ull;
    if (need <= ws_size) break;
    nb >>= 1;
  }
  const int NCB = nb*64;

  float* W = (float*)d_ws;
  size_t off = 0;
  float* TXC = W + off; off += 8336;
  float* TXS = W + off; off += 8336;
  float* TTC = W + off; off += 784;
  float* TTS = W + off; off += 784;
  float* ITC = W + off; off += 784;
  float* ITS = W + off; off += 784;
  float* WT0 = W + off; off += 1024;
  float* WT1 = W + off; off += 8192;
  float* WTC = W + off; off += 16384;
  float* VA  = W + off; off += (size_t)NCB*XT;
  float* VXR = W + off; off += (size_t)NCB*784;   // G real
  float* VXI = W + off; off += (size_t)NCB*784;   // G imag
  float* CVR = W + off; off += (size_t)256*NCB;   // cV partial half 0
  float* CVI = W + off; off += (size_t)256*NCB;
  float* COR = W + off; off += (size_t)256*NCB;   // spec out; doubles as cV partial half 1
  float* COI = W + off; off += (size_t)256*NCB;

  k_init<<<64, 256, 0, stream>>>(TXC,TXS,TTC,TTS,ITC,ITS,WT0,WT1,WTC, fc0_w, fc1_w, wconv);

  const int nch = NBTOT / nb;
  for (int ch = 0; ch < nch; ch++){
    int b0 = ch*nb;
    k_fc0<<<dim3((XT+255)/256, nb), 256, 0, stream>>>(u, xg, tg, par, WT0, fc0_b, VA, b0);
    k_dftxt<<<NCB*2, 256, 0, stream>>>(VA, TXC, TXS, TTC, TTS, CVR, CVI, COR, COI, NCB);
    for (int l=0; l<4; l++){
      k_spec<<<256, 256, 0, stream>>>(swr, swi, CVR, CVI, COR, COI, COR, COI, l, NCB);
      k_invG<<<NCB, 256, 0, stream>>>(COR, COI, ITC, ITS, VXR, VXI, NCB);
      k_conv<<<dim3(53, nb), 256, 0, stream>>>(VA, WTC, wbias, l);
      if (l < 3) k_inv2dft<1,1><<<NCB*2, 256, 0, stream>>>(VXR, VXI, TXC, TXS, TTC, TTS, VA, CVR, CVI, COR, COI, NCB);
      else       k_inv2dft<0,0><<<NCB*2, 256, 0, stream>>>(VXR, VXI, TXC, TXS, TTC, TTS, VA, CVR, CVI, COR, COI, NCB);
    }
    k_final<<<dim3(80, nb), 256, 0, stream>>>(VA, WT1, fc1_b, fc2_w, fc2_b, (float*)d_out, b0);
  }
}

// Round 12
// 1716.170 us; speedup vs baseline: 1.0646x; 1.0646x over previous
//
#include <hip/hip_runtime.h>
#include <math.h>

#define XDIM 521
#define TDIM 49
#define TPAD 52
#define XT (XDIM*TPAD)   /* 27092 */
#define NBTOT 32
#define NC 64
#define NS 512
#define NTO 40
#define NTIN 10
#define CIN 14
#define PI_D 3.14159265358979323846

typedef __attribute__((ext_vector_type(8))) short bf16x8;
typedef __attribute__((ext_vector_type(4))) float f32x4;
typedef unsigned short ushort_t;

__device__ __forceinline__ ushort_t f2bf(float x){
  union { float f; unsigned int u; } a; a.f = x;
  unsigned int r = a.u + 0x7FFF + ((a.u >> 16) & 1);   // round-to-nearest-even
  return (ushort_t)(r >> 16);
}
__device__ __forceinline__ float bf2f(ushort_t h){
  union { unsigned int u; float f; } a; a.u = ((unsigned int)h) << 16; return a.f;
}

// fast gelu: A&S 7.1.26 erf approximation, |err_erf| <= 1.5e-7
__device__ __forceinline__ float gelu_fast(float x){
  float z = x*0.70710678118654752440f;
  float az = fabsf(z);
  float t = __frcp_rn(fmaf(0.3275911f, az, 1.0f));
  float p = fmaf(1.061405429f, t, -1.453152027f);
  p = fmaf(p, t, 1.421413741f);
  p = fmaf(p, t, -0.284496736f);
  p = fmaf(p, t, 0.254829592f);
  p = p*t;
  float e = __expf(-az*az);
  float erfa = fmaf(-p, e, 1.0f);
  float erfz = (z < 0.f) ? -erfa : erfa;
  return 0.5f*x*(1.0f + erfz);
}

// ---------------- init: twiddles + small weight transforms + fc1 MFMA A-pack ----------------
__global__ void k_init(float* __restrict__ TXC, float* __restrict__ TXS,
                       float* __restrict__ TTC, float* __restrict__ TTS,
                       float* __restrict__ ITC, float* __restrict__ ITS,
                       float* __restrict__ WT0, float* __restrict__ WT1, float* __restrict__ WTC,
                       ushort_t* __restrict__ AH, ushort_t* __restrict__ AL,
                       const float* __restrict__ fc0_w, const float* __restrict__ fc1_w,
                       const float* __restrict__ w_conv){
  int i = blockIdx.x*256 + threadIdx.x;
  if (i < XDIM*16){
    int x = i >> 4, kx = i & 15;
    double ang = 2.0*PI_D*(double)((x*kx)%XDIM)/(double)XDIM;
    TXC[i] = (float)cos(ang);
    TXS[i] = (float)sin(ang);
  }
  if (i < TDIM*16){
    int t = i >> 4, kt = i & 15;
    double ang = 2.0*PI_D*(double)((t*kt)%TDIM)/(double)TDIM;
    TTC[i] = (float)cos(ang);
    TTS[i] = (float)sin(ang);
    double nrm = ((kt==0)?1.0:2.0)/(double)(XDIM*TDIM);
    ITC[i] = (float)(nrm*cos(ang));
    ITS[i] = (float)(nrm*sin(ang));
  }
  if (i < 64*16){               // fc0_w (14,64) -> WT0[c][16]
    int c = i >> 4, k = i & 15;
    WT0[i] = (k < CIN) ? fc0_w[k*64 + c] : 0.f;
  }
  if (i < 128*64){              // fc1_w (64,128) -> WT1[j][c]
    int j = i >> 6, c = i & 63;
    WT1[i] = fc1_w[c*128 + j];
  }
  if (i < 4*64*64){             // w_conv (4,o,c) -> WTC[l][c][o]
    int l = i >> 12, r = i & 4095, c = r >> 6, o = r & 63;
    WTC[i] = w_conv[(l*64 + o)*64 + c];
  }
  if (i < 8192){                // fc1 A-frag pack: idx = ((jt*2+ks)*64 + lane)*8 + ii
    int ii = i & 7, lane = (i >> 3) & 63, kjt = i >> 9;
    int jt = kjt >> 1, ks = kjt & 1;
    int j = jt*16 + (lane & 15);
    int c = ks*32 + (lane >> 4)*8 + ii;
    float wv = fc1_w[c*128 + j];
    ushort_t hi = f2bf(wv);
    AH[i] = hi;
    AL[i] = f2bf(wv - bf2f(hi));
  }
}

// ---------------- fc0 + grid-feature build + transpose + pad (position-parallel) ----------------
__global__ void k_fc0(const float* __restrict__ u, const float* __restrict__ xg,
                      const float* __restrict__ tg, const float* __restrict__ par,
                      const float* __restrict__ WT0, const float* __restrict__ fc0_b,
                      float* __restrict__ v, int b0){
  int bl = blockIdx.y;
  int b  = b0 + bl;
  int p = blockIdx.x*256 + threadIdx.x;
  if (p >= XT) return;
  int x = p / TPAD, t = p - x*TPAD;
  bool valid = (x < NS) && (t < NTO);
  float in[CIN];
  if (valid){
    #pragma unroll
    for (int k=0;k<NTIN;k++) in[k] = u[((size_t)(b*NS+x))*NTIN + k];
    in[10] = par[b*2+0]; in[11] = par[b*2+1];
    in[12] = xg[b*NS + x];
    in[13] = tg[b*NTO + t];
  } else {
    #pragma unroll
    for (int k=0;k<CIN;k++) in[k] = 0.f;
  }
  size_t base = ((size_t)bl*NC)*XT + p;
  for (int c=0;c<NC;c++){
    float acc = valid ? fc0_b[c] : 0.f;
    #pragma unroll
    for (int k=0;k<CIN;k++) acc = fmaf(in[k], WT0[c*16+k], acc);
    v[base + (size_t)c*XT] = acc;
  }
}

// ---- reduce tail: combine this block's 4-wave DFT-x partials, T-DFT, write partial cV ----
__device__ __forceinline__ void dft_reduce_emit(
    float (&ar)[16], float (&ai)[16], int w, int t,
    const float* __restrict__ TTC, const float* __restrict__ TTS,
    float* __restrict__ cVR, float* __restrict__ cVI, int bo, int NCB){
  __shared__ float redR[4*16*50], redI[4*16*50];
  if (t < TDIM){
    #pragma unroll
    for (int kx=0;kx<16;kx++){
      redR[(w*16+kx)*50 + t] = ar[kx];
      redI[(w*16+kx)*50 + t] = ai[kx];
    }
  }
  __syncthreads();
  int tid = w*64 + t;
  for (int q = tid; q < 784; q += 256){
    int kx = q/49, tt = q - kx*49;
    int idx = kx*50 + tt;
    float sR = redR[idx] + redR[800+idx] + redR[1600+idx] + redR[2400+idx];
    float sI = redI[idx] + redI[800+idx] + redI[1600+idx] + redI[2400+idx];
    redR[idx] = sR; redI[idx] = sI;
  }
  __syncthreads();
  int kx = tid >> 4, kt = tid & 15;
  float accR=0.f, accI=0.f;
  for (int tt=0; tt<TDIM; tt++){
    float vr = redR[kx*50+tt], vi = redI[kx*50+tt];
    float c = TTC[tt*16+kt], s = TTS[tt*16+kt];
    accR += vr*c + vi*s;
    accI += vi*c - vr*s;
  }
  cVR[(size_t)tid*NCB + bo] = accR;
  cVI[(size_t)tid*NCB + bo] = accI;
}

// ---------------- standalone DFT-x + DFT-t of a plane (layer 0), mirror-paired, 2-way split ----
__global__ void __launch_bounds__(256) k_dftxt(const float* __restrict__ v,
    const float* __restrict__ TXC, const float* __restrict__ TXS,
    const float* __restrict__ TTC, const float* __restrict__ TTS,
    float* __restrict__ cVR0, float* __restrict__ cVI0,
    float* __restrict__ cVR1, float* __restrict__ cVI1, int NCB){
  int bo = blockIdx.x >> 1, h = blockIdx.x & 1;
  int w = threadIdx.x >> 6, t = threadIdx.x & 63;
  bool act = (t < TDIM);
  const float* vp = v + (size_t)bo*XT + (act ? t : 0);
  float ar[16], ai[16];
  #pragma unroll
  for (int k=0;k<16;k++){ ar[k]=0.f; ai[k]=0.f; }
  if (h == 0 && w == 0){
    float v0 = act ? vp[0] : 0.f;      // x=0: c=1, s=0 for all kx
    #pragma unroll
    for (int k=0;k<16;k++) ar[k] += v0;
  }
  int chunk = h*4 + w;                  // 0..7 over 260 mirror pairs
  int p0 = 1 + (chunk*65)/2, p1 = 1 + ((chunk+1)*65)/2;
  for (int p=p0; p<p1; p++){
    int xa = p, xb = XDIM - p;
    float va = act ? vp[xa*TPAD] : 0.f;
    float vbv= act ? vp[xb*TPAD] : 0.f;
    float sp = va + vbv, sm = va - vbv;
    const float4 tc0 = *reinterpret_cast<const float4*>(TXC + xa*16 + 0);
    const float4 tc1 = *reinterpret_cast<const float4*>(TXC + xa*16 + 4);
    const float4 tc2 = *reinterpret_cast<const float4*>(TXC + xa*16 + 8);
    const float4 tc3 = *reinterpret_cast<const float4*>(TXC + xa*16 + 12);
    const float4 ts0 = *reinterpret_cast<const float4*>(TXS + xa*16 + 0);
    const float4 ts1 = *reinterpret_cast<const float4*>(TXS + xa*16 + 4);
    const float4 ts2 = *reinterpret_cast<const float4*>(TXS + xa*16 + 8);
    const float4 ts3 = *reinterpret_cast<const float4*>(TXS + xa*16 + 12);
    ar[0]  = fmaf(sp, tc0.x, ar[0]);  ai[0]  = fmaf(-sm, ts0.x, ai[0]);
    ar[1]  = fmaf(sp, tc0.y, ar[1]);  ai[1]  = fmaf(-sm, ts0.y, ai[1]);
    ar[2]  = fmaf(sp, tc0.z, ar[2]);  ai[2]  = fmaf(-sm, ts0.z, ai[2]);
    ar[3]  = fmaf(sp, tc0.w, ar[3]);  ai[3]  = fmaf(-sm, ts0.w, ai[3]);
    ar[4]  = fmaf(sp, tc1.x, ar[4]);  ai[4]  = fmaf(-sm, ts1.x, ai[4]);
    ar[5]  = fmaf(sp, tc1.y, ar[5]);  ai[5]  = fmaf(-sm, ts1.y, ai[5]);
    ar[6]  = fmaf(sp, tc1.z, ar[6]);  ai[6]  = fmaf(-sm, ts1.z, ai[6]);
    ar[7]  = fmaf(sp, tc1.w, ar[7]);  ai[7]  = fmaf(-sm, ts1.w, ai[7]);
    ar[8]  = fmaf(sp, tc2.x, ar[8]);  ai[8]  = fmaf(-sm, ts2.x, ai[8]);
    ar[9]  = fmaf(sp, tc2.y, ar[9]);  ai[9]  = fmaf(-sm, ts2.y, ai[9]);
    ar[10] = fmaf(sp, tc2.z, ar[10]); ai[10] = fmaf(-sm, ts2.z, ai[10]);
    ar[11] = fmaf(sp, tc2.w, ar[11]); ai[11] = fmaf(-sm, ts2.w, ai[11]);
    ar[12] = fmaf(sp, tc3.x, ar[12]); ai[12] = fmaf(-sm, ts3.x, ai[12]);
    ar[13] = fmaf(sp, tc3.y, ar[13]); ai[13] = fmaf(-sm, ts3.y, ai[13]);
    ar[14] = fmaf(sp, tc3.z, ar[14]); ai[14] = fmaf(-sm, ts3.z, ai[14]);
    ar[15] = fmaf(sp, tc3.w, ar[15]); ai[15] = fmaf(-sm, ts3.w, ai[15]);
  }
  dft_reduce_emit(ar, ai, w, t, TTC, TTS, h ? cVR1 : cVR0, h ? cVI1 : cVI0, bo, NCB);
}

// ---------------- per-mode 64x64 complex channel mix (cV = half0 + half1) ----------------
__global__ void k_spec(const float* __restrict__ swr, const float* __restrict__ swi,
                       const float* __restrict__ cVR0, const float* __restrict__ cVI0,
                       const float* __restrict__ cVR1, const float* __restrict__ cVI1,
                       float* __restrict__ cOR, float* __restrict__ cOI, int l, int NCB){
  int m = blockIdx.x;           // 0..255 = kx*16+kt
  __shared__ float wr[4096], wi[4096];
  __shared__ float vr[32*65], vi[32*65];
  const size_t wb = (size_t)l*64*64*256 + m;
  for (int q = threadIdx.x; q < 4096; q += 256){
    wr[q] = swr[wb + (size_t)q*256];
    wi[q] = swi[wb + (size_t)q*256];
  }
  for (int q = threadIdx.x; q < NCB; q += 256){
    int b=q>>6, i=q&63;
    vr[b*65+i] = cVR0[(size_t)m*NCB+q] + cVR1[(size_t)m*NCB+q];
    vi[b*65+i] = cVI0[(size_t)m*NCB+q] + cVI1[(size_t)m*NCB+q];
  }
  __syncthreads();
  int b = threadIdx.x >> 3, og = threadIdx.x & 7;
  if (b*64 < NCB){
    float oR[8], oI[8];
    #pragma unroll
    for (int j=0;j<8;j++){ oR[j]=0.f; oI[j]=0.f; }
    for (int i=0;i<64;i++){
      float arv = vr[b*65+i], aiv = vi[b*65+i];
      #pragma unroll
      for (int j=0;j<8;j++){
        float wrv = wr[i*64 + og*8 + j], wiv = wi[i*64 + og*8 + j];
        oR[j] = fmaf(arv,wrv,fmaf(-aiv,wiv,oR[j]));
        oI[j] = fmaf(arv,wiv,fmaf( aiv,wrv,oI[j]));
      }
    }
    #pragma unroll
    for (int j=0;j<8;j++){
      cOR[(size_t)m*NCB + b*64 + og*8 + j] = oR[j];
      cOI[(size_t)m*NCB + b*64 + og*8 + j] = oI[j];
    }
  }
}

// ---------------- inverse part 1: kt -> t expansion (tiny), G into VX buffers ----------------
__global__ void __launch_bounds__(256) k_invG(const float* __restrict__ cOR, const float* __restrict__ cOI,
    const float* __restrict__ ITC, const float* __restrict__ ITS,
    float* __restrict__ GR, float* __restrict__ GI, int NCB){
  int bo = blockIdx.x;
  __shared__ float lcr[256], lci[256];
  int q = threadIdx.x;
  lcr[q] = cOR[(size_t)q*NCB + bo];
  lci[q] = cOI[(size_t)q*NCB + bo];
  __syncthreads();
  int kx = q >> 4, tq = q & 15;
  for (int t = tq; t < TDIM; t += 16){
    float gr=0.f, gi=0.f;
    #pragma unroll
    for (int kt=0;kt<16;kt++){
      float cr = lcr[kx*16+kt], ci = lci[kx*16+kt];
      float wc = ITC[t*16+kt], ws = ITS[t*16+kt];
      gr = fmaf(cr,wc,fmaf(-ci,ws,gr));
      gi = fmaf(cr,ws,fmaf( ci,wc,gi));
    }
    GR[(size_t)bo*784 + kx*TDIM + t] = gr;
    GI[(size_t)bo*784 + kx*TDIM + t] = gi;
  }
}

// ---------------- pointwise conv, IN-PLACE: v <- W*v + bias (u2 stored) ----------------
__global__ void __launch_bounds__(256) k_conv(float* __restrict__ v,
    const float* __restrict__ WTC, const float* __restrict__ w_bias, int l){
  int bl = blockIdx.y;
  int p = blockIdx.x*512 + threadIdx.x*2;
  if (p >= XT) return;
  const float* wl = WTC + l*4096;    // [c][o]
  float a0[64], a1[64];
  #pragma unroll
  for (int o=0;o<64;o++){ a0[o]=0.f; a1[o]=0.f; }
  const size_t bb = (size_t)bl*NC*XT;
  for (int c=0;c<NC;c++){
    const float2 vv = *reinterpret_cast<const float2*>(v + bb + (size_t)c*XT + p);
    #pragma unroll
    for (int o=0;o<64;o++){
      float wv = wl[c*64+o];          // uniform -> s_load
      a0[o] = fmaf(vv.x, wv, a0[o]);
      a1[o] = fmaf(vv.y, wv, a1[o]);
    }
  }
  #pragma unroll
  for (int o=0;o<64;o++){
    float bias = w_bias[l*64+o];
    float2 rr; rr.x = a0[o]+bias; rr.y = a1[o]+bias;
    *reinterpret_cast<float2*>(v + bb + (size_t)o*XT + p) = rr;
  }
}

// ---- fused inverse-x (mirror-paired) + add + gelu + in-register DFT emit, 2-way split ----
template<int GELU, int EMIT>
__global__ void __launch_bounds__(256) k_inv2dft(const float* __restrict__ GR, const float* __restrict__ GI,
    const float* __restrict__ TXC, const float* __restrict__ TXS,
    const float* __restrict__ TTC, const float* __restrict__ TTS,
    float* __restrict__ v,
    float* __restrict__ cVR0, float* __restrict__ cVI0,
    float* __restrict__ cVR1, float* __restrict__ cVI1, int NCB){
  int bo = blockIdx.x >> 1, h = blockIdx.x & 1;
  int w = threadIdx.x >> 6, t = threadIdx.x & 63;
  bool act = (t < TDIM);
  int tcl = act ? t : 0;
  float gr[16], gi[16];
  #pragma unroll
  for (int kx=0;kx<16;kx++){
    gr[kx] = GR[(size_t)bo*784 + kx*TDIM + tcl];
    gi[kx] = GI[(size_t)bo*784 + kx*TDIM + tcl];
  }
  float ar[16], ai[16];
  #pragma unroll
  for (int k=0;k<16;k++){ ar[k]=0.f; ai[k]=0.f; }
  float* vb = v + (size_t)bo*XT;
  if (h == 0 && w == 0){                        // x = 0: c=1, s=0
    float s1 = 0.f;
    #pragma unroll
    for (int k=0;k<16;k++) s1 += gr[k];
    float r = 0.f;
    if (act){
      r = s1 + vb[t];
      if (GELU) r = gelu_fast(r);
    }
    if (t < TPAD) vb[t] = r;
    if (EMIT){
      #pragma unroll
      for (int k=0;k<16;k++) ar[k] += r;
    }
  }
  int chunk = h*4 + w;                  // 0..7 over 260 mirror pairs
  int p0 = 1 + (chunk*65)/2, p1 = 1 + ((chunk+1)*65)/2;
  for (int p=p0; p<p1; p++){
    int xa = p, xb = XDIM - p;
    const float4 tc0 = *reinterpret_cast<const float4*>(TXC + xa*16 + 0);
    const float4 tc1 = *reinterpret_cast<const float4*>(TXC + xa*16 + 4);
    const float4 tc2 = *reinterpret_cast<const float4*>(TXC + xa*16 + 8);
    const float4 tc3 = *reinterpret_cast<const float4*>(TXC + xa*16 + 12);
    const float4 ts0 = *reinterpret_cast<const float4*>(TXS + xa*16 + 0);
    const float4 ts1 = *reinterpret_cast<const float4*>(TXS + xa*16 + 4);
    const float4 ts2 = *reinterpret_cast<const float4*>(TXS + xa*16 + 8);
    const float4 ts3 = *reinterpret_cast<const float4*>(TXS + xa*16 + 12);
    float s1, s2;
    s1  = gr[0]*tc0.x;             s2  = gi[0]*ts0.x;
    s1  = fmaf(gr[1],  tc0.y, s1); s2  = fmaf(gi[1],  ts0.y, s2);
    s1  = fmaf(gr[2],  tc0.z, s1); s2  = fmaf(gi[2],  ts0.z, s2);
    s1  = fmaf(gr[3],  tc0.w, s1); s2  = fmaf(gi[3],  ts0.w, s2);
    s1  = fmaf(gr[4],  tc1.x, s1); s2  = fmaf(gi[4],  ts1.x, s2);
    s1  = fmaf(gr[5],  tc1.y, s1); s2  = fmaf(gi[5],  ts1.y, s2);
    s1  = fmaf(gr[6],  tc1.z, s1); s2  = fmaf(gi[6],  ts1.z, s2);
    s1  = fmaf(gr[7],  tc1.w, s1); s2  = fmaf(gi[7],  ts1.w, s2);
    s1  = fmaf(gr[8],  tc2.x, s1); s2  = fmaf(gi[8],  ts2.x, s2);
    s1  = fmaf(gr[9],  tc2.y, s1); s2  = fmaf(gi[9],  ts2.y, s2);
    s1  = fmaf(gr[10], tc2.z, s1); s2  = fmaf(gi[10], ts2.z, s2);
    s1  = fmaf(gr[11], tc2.w, s1); s2  = fmaf(gi[11], ts2.w, s2);
    s1  = fmaf(gr[12], tc3.x, s1); s2  = fmaf(gi[12], ts3.x, s2);
    s1  = fmaf(gr[13], tc3.y, s1); s2  = fmaf(gi[13], ts3.y, s2);
    s1  = fmaf(gr[14], tc3.z, s1); s2  = fmaf(gi[14], ts3.z, s2);
    s1  = fmaf(gr[15], tc3.w, s1); s2  = fmaf(gi[15], ts3.w, s2);
    float accA = s1 - s2, accB = s1 + s2;
    float rA = 0.f, rB = 0.f;
    if (act){
      rA = accA + vb[(size_t)xa*TPAD + t];
      rB = accB + vb[(size_t)xb*TPAD + t];
      if (GELU){ rA = gelu_fast(rA); rB = gelu_fast(rB); }
    }
    if (t < TPAD){
      vb[(size_t)xa*TPAD + t] = rA;
      vb[(size_t)xb*TPAD + t] = rB;
    }
    if (EMIT){
      float sp = rA + rB, sm = rA - rB;
      ar[0]  = fmaf(sp, tc0.x, ar[0]);  ai[0]  = fmaf(-sm, ts0.x, ai[0]);
      ar[1]  = fmaf(sp, tc0.y, ar[1]);  ai[1]  = fmaf(-sm, ts0.y, ai[1]);
      ar[2]  = fmaf(sp, tc0.z, ar[2]);  ai[2]  = fmaf(-sm, ts0.z, ai[2]);
      ar[3]  = fmaf(sp, tc0.w, ar[3]);  ai[3]  = fmaf(-sm, ts0.w, ai[3]);
      ar[4]  = fmaf(sp, tc1.x, ar[4]);  ai[4]  = fmaf(-sm, ts1.x, ai[4]);
      ar[5]  = fmaf(sp, tc1.y, ar[5]);  ai[5]  = fmaf(-sm, ts1.y, ai[5]);
      ar[6]  = fmaf(sp, tc1.z, ar[6]);  ai[6]  = fmaf(-sm, ts1.z, ai[6]);
      ar[7]  = fmaf(sp, tc1.w, ar[7]);  ai[7]  = fmaf(-sm, ts1.w, ai[7]);
      ar[8]  = fmaf(sp, tc2.x, ar[8]);  ai[8]  = fmaf(-sm, ts2.x, ai[8]);
      ar[9]  = fmaf(sp, tc2.y, ar[9]);  ai[9]  = fmaf(-sm, ts2.y, ai[9]);
      ar[10] = fmaf(sp, tc2.z, ar[10]); ai[10] = fmaf(-sm, ts2.z, ai[10]);
      ar[11] = fmaf(sp, tc2.w, ar[11]); ai[11] = fmaf(-sm, ts2.w, ai[11]);
      ar[12] = fmaf(sp, tc3.x, ar[12]); ai[12] = fmaf(-sm, ts3.x, ai[12]);
      ar[13] = fmaf(sp, tc3.y, ar[13]); ai[13] = fmaf(-sm, ts3.y, ai[13]);
      ar[14] = fmaf(sp, tc3.z, ar[14]); ai[14] = fmaf(-sm, ts3.z, ai[14]);
      ar[15] = fmaf(sp, tc3.w, ar[15]); ai[15] = fmaf(-sm, ts3.w, ai[15]);
    }
  }
  if (EMIT) dft_reduce_emit(ar, ai, w, t, TTC, TTS, h ? cVR1 : cVR0, h ? cVI1 : cVI0, bo, NCB);
}

// ---------------- crop + fc1(MFMA split-bf16) + gelu + fc2 ----------------
// wave = one 16-position tile; A pre-packed (hi/lo) in exact frag layout
__global__ void __launch_bounds__(256) k_final(const float* __restrict__ v,
    const ushort_t* __restrict__ AH, const ushort_t* __restrict__ AL,
    const float* __restrict__ fc1_b, const float* __restrict__ fc2_w,
    const float* __restrict__ fc2_b, float* __restrict__ out, int b0){
  int bl = blockIdx.y;
  int wv = threadIdx.x >> 6, l = threadIdx.x & 63;
  int col = l & 15, g = l >> 4;
  int tile = blockIdx.x*4 + wv;              // 0..1279  (20480/16)
  int pp = tile*16 + col;
  int s = pp / NTO, to = pp - s*NTO;
  const float* vb = v + (size_t)bl*NC*XT + (size_t)s*TPAD + to;
  // B fragments (activations), split precision
  bf16x8 Bh[2], Bl[2];
  #pragma unroll
  for (int ks=0; ks<2; ks++){
    #pragma unroll
    for (int i=0; i<8; i++){
      int c = ks*32 + g*8 + i;
      float x = vb[(size_t)c*XT];
      ushort_t hi = f2bf(x);
      ushort_t lo = f2bf(x - bf2f(hi));
      Bh[ks][i] = (short)hi;
      Bl[ks][i] = (short)lo;
    }
  }
  float partial = 0.f;
  #pragma unroll
  for (int jt=0; jt<8; jt++){
    f32x4 acc = {0.f, 0.f, 0.f, 0.f};
    #pragma unroll
    for (int ks=0; ks<2; ks++){
      int aidx = ((jt*2 + ks)*64 + l)*8;
      bf16x8 Ah = *reinterpret_cast<const bf16x8*>(AH + aidx);
      bf16x8 Al = *reinterpret_cast<const bf16x8*>(AL + aidx);
      acc = __builtin_amdgcn_mfma_f32_16x16x32_bf16(Ah, Bh[ks], acc, 0, 0, 0);
      acc = __builtin_amdgcn_mfma_f32_16x16x32_bf16(Ah, Bl[ks], acc, 0, 0, 0);
      acc = __builtin_amdgcn_mfma_f32_16x16x32_bf16(Al, Bh[ks], acc, 0, 0, 0);
    }
    #pragma unroll
    for (int reg=0; reg<4; reg++){
      int j = jt*16 + g*4 + reg;
      float hh = acc[reg] + fc1_b[j];
      hh = gelu_fast(hh);
      partial = fmaf(hh, fc2_w[j], partial);
    }
  }
  partial += __shfl_xor(partial, 16, 64);
  partial += __shfl_xor(partial, 32, 64);
  if (g == 0) out[((size_t)(b0+bl))*20480 + pp] = partial + fc2_b[0];
}

extern "C" void kernel_launch(void* const* d_in, const int* in_sizes, int n_in,
                              void* d_out, int out_size, void* d_ws, size_t ws_size,
                              hipStream_t stream){
  const float* u     = (const float*)d_in[0];
  const float* xg    = (const float*)d_in[1];
  const float* tg    = (const float*)d_in[2];
  const float* par   = (const float*)d_in[3];
  const float* fc0_w = (const float*)d_in[4];
  const float* fc0_b = (const float*)d_in[5];
  const float* swr   = (const float*)d_in[6];
  const float* swi   = (const float*)d_in[7];
  const float* wconv = (const float*)d_in[8];
  const float* wbias = (const float*)d_in[9];
  const float* fc1_w = (const float*)d_in[10];
  const float* fc1_b = (const float*)d_in[11];
  const float* fc2_w = (const float*)d_in[12];
  const float* fc2_b = (const float*)d_in[13];

  // pick largest batch chunk whose workspace fits ws_size (fixed part grew by 8192 floats)
  int nb = NBTOT;
  while (nb > 1){
    size_t need = (53600ull + (size_t)nb*64ull*29684ull) * 4ull;
    if (need <= ws_size) break;
    nb >>= 1;
  }
  const int NCB = nb*64;

  float* W = (float*)d_ws;
  size_t off = 0;
  float* TXC = W + off; off += 8336;
  float* TXS = W + off; off += 8336;
  float* TTC = W + off; off += 784;
  float* TTS = W + off; off += 784;
  float* ITC = W + off; off += 784;
  float* ITS = W + off; off += 784;
  float* WT0 = W + off; off += 1024;
  float* WT1 = W + off; off += 8192;
  float* WTC = W + off; off += 16384;
  ushort_t* AH = (ushort_t*)(W + off); off += 4096;   // 8192 bf16
  ushort_t* AL = (ushort_t*)(W + off); off += 4096;   // 8192 bf16
  float* VA  = W + off; off += (size_t)NCB*XT;
  float* VXR = W + off; off += (size_t)NCB*784;   // G real
  float* VXI = W + off; off += (size_t)NCB*784;   // G imag
  float* CVR = W + off; off += (size_t)256*NCB;   // cV partial half 0
  float* CVI = W + off; off += (size_t)256*NCB;
  float* COR = W + off; off += (size_t)256*NCB;   // spec out; doubles as cV partial half 1
  float* COI = W + off; off += (size_t)256*NCB;

  k_init<<<64, 256, 0, stream>>>(TXC,TXS,TTC,TTS,ITC,ITS,WT0,WT1,WTC, AH, AL, fc0_w, fc1_w, wconv);

  const int nch = NBTOT / nb;
  for (int ch = 0; ch < nch; ch++){
    int b0 = ch*nb;
    k_fc0<<<dim3((XT+255)/256, nb), 256, 0, stream>>>(u, xg, tg, par, WT0, fc0_b, VA, b0);
    k_dftxt<<<NCB*2, 256, 0, stream>>>(VA, TXC, TXS, TTC, TTS, CVR, CVI, COR, COI, NCB);
    for (int l=0; l<4; l++){
      k_spec<<<256, 256, 0, stream>>>(swr, swi, CVR, CVI, COR, COI, COR, COI, l, NCB);
      k_invG<<<NCB, 256, 0, stream>>>(COR, COI, ITC, ITS, VXR, VXI, NCB);
      k_conv<<<dim3(53, nb), 256, 0, stream>>>(VA, WTC, wbias, l);
      if (l < 3) k_inv2dft<1,1><<<NCB*2, 256, 0, stream>>>(VXR, VXI, TXC, TXS, TTC, TTS, VA, CVR, CVI, COR, COI, NCB);
      else       k_inv2dft<0,0><<<NCB*2, 256, 0, stream>>>(VXR, VXI, TXC, TXS, TTC, TTS, VA, CVR, CVI, COR, COI, NCB);
    }
    k_final<<<dim3(320, nb), 256, 0, stream>>>(VA, AH, AL, fc1_b, fc2_w, fc2_b, (float*)d_out, b0);
  }
}